// Round 10
// baseline (269.889 us; speedup 1.0000x reference)
//
#include <hip/hip_runtime.h>
#include <math.h>

#define NN 100000
#define MM 50000
#define EE 600000
#define DD 128
#define NB 196  // ceil(MM/256)

typedef short bf16x8 __attribute__((ext_vector_type(8)));
typedef float f32x4 __attribute__((ext_vector_type(4)));

// ---- bf16 helpers (upper 16 bits of f32; RNE rounding) ----
__device__ __forceinline__ float bl(unsigned u) { return __uint_as_float(u << 16); }
__device__ __forceinline__ float bh(unsigned u) { return __uint_as_float(u & 0xFFFF0000u); }
__device__ __forceinline__ unsigned rne(float f) {
    unsigned u = __float_as_uint(f);
    return (u + 0x7FFFu + ((u >> 16) & 1u)) >> 16;
}
__device__ __forceinline__ unsigned pk2(float a, float b) { return rne(a) | (rne(b) << 16); }

// a[0..7] += v * bf16x8(u)   (spmm inner op)
__device__ __forceinline__ void fmab8(float v, uint4 u, float* a) {
    a[0] = fmaf(v, bl(u.x), a[0]); a[1] = fmaf(v, bh(u.x), a[1]);
    a[2] = fmaf(v, bl(u.y), a[2]); a[3] = fmaf(v, bh(u.y), a[3]);
    a[4] = fmaf(v, bl(u.z), a[4]); a[5] = fmaf(v, bh(u.z), a[5]);
    a[6] = fmaf(v, bl(u.w), a[6]); a[7] = fmaf(v, bh(u.w), a[7]);
}

__device__ __forceinline__ void fma21(float h, const float* wrow, float* a) {
    #pragma unroll
    for (int j = 0; j < 21; ++j) a[j] = fmaf(h, wrow[j], a[j]);
}

// --- degree+count via ONE packed 64-bit atomic per edge ---
__global__ void deg_count_kernel(const int* __restrict__ row, const float* __restrict__ val,
                                 unsigned long long* __restrict__ dcpack,
                                 int* __restrict__ slot, int* __restrict__ invidx) {
    int e = blockIdx.x * 256 + threadIdx.x;
    if (e < NN) invidx[e] = -1;
    if (e < EE) {
        int r = row[e];
        unsigned long long add = (1ULL << 44) | (unsigned long long)(val[e] * 4294967296.0f);
        unsigned long long old = atomicAdd(&dcpack[r], add);
        slot[e] = (int)(old >> 44);
    }
}

// --- fused: unpack deg/cnt; dis; invidx; scanA ---
__global__ void fused_setup_kernel(const unsigned long long* __restrict__ dcpack,
                                   float* __restrict__ dis,
                                   const int* __restrict__ index, int* __restrict__ invidx,
                                   int* __restrict__ cnt, int* __restrict__ partial,
                                   int* __restrict__ bsum) {
    __shared__ int ws[4];
    int tid = threadIdx.x, lane = tid & 63, w = tid >> 6;
    int i = blockIdx.x * 256 + tid;
    int v = 0;
    if (i < MM) {
        unsigned long long pkv = dcpack[i];
        v = (int)(pkv >> 44);
        float dsum = (float)(pkv & ((1ULL << 44) - 1)) * (1.0f / 4294967296.0f);
        dis[i] = rsqrtf(dsum + 1e-8f);
        invidx[index[i]] = i;
        cnt[i] = v;
    }
    int x = v;
    #pragma unroll
    for (int off = 1; off < 64; off <<= 1) {
        int t = __shfl_up(x, off, 64);
        if (lane >= off) x += t;
    }
    if (lane == 63) ws[w] = x;
    __syncthreads();
    int add = 0;
    for (int q = 0; q < w; ++q) add += ws[q];
    x += add;
    if (i < MM) partial[i] = x;
    if (tid == 255) bsum[blockIdx.x] = x;
}

__global__ void scanB_kernel(const int* __restrict__ bsum, int* __restrict__ boff) {
    int lane = threadIdx.x;  // 64 threads
    int carry = 0;
    for (int base = 0; base < NB; base += 64) {
        int v = (base + lane < NB) ? bsum[base + lane] : 0;
        int x = v;
        #pragma unroll
        for (int off = 1; off < 64; off <<= 1) {
            int t = __shfl_up(x, off, 64);
            if (lane >= off) x += t;
        }
        if (base + lane < NB) boff[base + lane] = carry + x - v;
        carry += __shfl(x, 63);
    }
}

__global__ void scanC_kernel(const int* __restrict__ partial, const int* __restrict__ cnt,
                             const int* __restrict__ boff, int* __restrict__ rowptr) {
    int i = blockIdx.x * 256 + threadIdx.x;
    if (i < MM) rowptr[i] = partial[i] - cnt[i] + boff[i >> 8];
    if (i == 0) rowptr[MM] = EE;
}

// --- bucket edges by row (atomic-free) ---
__global__ void scatter_kernel(const int* __restrict__ row, const int* __restrict__ col,
                               const float* __restrict__ val, const float* __restrict__ dis,
                               const int* __restrict__ rowptr, const int* __restrict__ slot,
                               int* __restrict__ col_s, float* __restrict__ val_s) {
    int e = blockIdx.x * 256 + threadIdx.x;
    if (e < EE) {
        int r = row[e], c = col[e];
        int pos = rowptr[r] + slot[e];
        col_s[pos] = c;
        val_s[pos] = val[e] * dis[r] * dis[c];
    }
}

// --- X0b = bf16(features[index]); W1b/W2b = transposed packed bf16 weights ---
__global__ void cvt_kernel(const float* __restrict__ feat, const int* __restrict__ index,
                           unsigned* __restrict__ X0b,
                           const float* __restrict__ W1, const float* __restrict__ W2,
                           unsigned* __restrict__ W1b, unsigned* __restrict__ W2b) {
    int i = blockIdx.x * 256 + threadIdx.x;
    if (i < MM * 64) {
        int node = i >> 6, k2 = i & 63;
        int idx = index[node];
        float2 f = ((const float2*)feat)[(size_t)idx * 64 + k2];
        X0b[i] = pk2(f.x, f.y);
    }
    if (i < 4096) {          // W1^T: [j=0..63][kp=0..63]  (K=128 -> 64 k-pairs!)
        int j = i >> 6, kp = i & 63;
        W1b[i] = pk2(W1[(2 * kp) * 64 + j], W1[(2 * kp + 1) * 64 + j]);
    } else if (i < 5120) {   // W2^T: [j=0..31][kp=0..31]  (K=64 -> 32 k-pairs)
        int u = i - 4096;
        int j = u >> 5, kp = u & 31;
        W2b[u] = pk2(W2[(2 * kp) * 32 + j], W2[(2 * kp + 1) * 32 + j]);
    }
}

// --- SpMM on bf16 tables: 16-lane group per row, 4 groups/wave; 1 uint4 gather/edge ---
__global__ __launch_bounds__(256) void spmm_kernel(
    const int* __restrict__ rowptr, const int* __restrict__ cols,
    const float* __restrict__ vals, const unsigned short* __restrict__ X,
    unsigned short* __restrict__ Y) {
    int lane = threadIdx.x & 63;
    int wid = threadIdx.x >> 6;
    int g = lane >> 4, sub = lane & 15;
    int r = blockIdx.x * 16 + wid * 4 + g;
    bool valid = (r < MM);
    int rc = valid ? r : (MM - 1);
    int s = rowptr[rc], e = rowptr[rc + 1];
    const uint4* __restrict__ X4 = (const uint4*)X;
    float a[8] = {0.f, 0.f, 0.f, 0.f, 0.f, 0.f, 0.f, 0.f};
    for (int base = s; base < e; base += 16) {
        int cnt = min(16, e - base);
        int c = 0; float v = 0.f;
        if (sub < cnt) { c = cols[base + sub]; v = vals[base + sub]; }
        int j = 0;
        for (; j + 4 <= cnt; j += 4) {
            int c0 = __shfl(c, g * 16 + j);     float v0 = __shfl(v, g * 16 + j);
            int c1 = __shfl(c, g * 16 + j + 1); float v1 = __shfl(v, g * 16 + j + 1);
            int c2 = __shfl(c, g * 16 + j + 2); float v2 = __shfl(v, g * 16 + j + 2);
            int c3 = __shfl(c, g * 16 + j + 3); float v3 = __shfl(v, g * 16 + j + 3);
            uint4 u0 = X4[(size_t)c0 * 16 + sub];
            uint4 u1 = X4[(size_t)c1 * 16 + sub];
            uint4 u2 = X4[(size_t)c2 * 16 + sub];
            uint4 u3 = X4[(size_t)c3 * 16 + sub];
            fmab8(v0, u0, a);
            fmab8(v1, u1, a);
            fmab8(v2, u2, a);
            fmab8(v3, u3, a);
        }
        for (; j < cnt; ++j) {
            int cc = __shfl(c, g * 16 + j); float vv = __shfl(v, g * 16 + j);
            uint4 u0 = X4[(size_t)cc * 16 + sub];
            fmab8(vv, u0, a);
        }
    }
    if (valid) {
        uint4 o;
        o.x = pk2(a[0], a[1]); o.y = pk2(a[2], a[3]);
        o.z = pk2(a[4], a[5]); o.w = pk2(a[6], a[7]);
        ((uint4*)Y)[(size_t)r * 16 + sub] = o;
    }
}

// --- MFMA MLP head: 64 nodes/block, 4 waves x 16 nodes; pre-packed bf16 weights.
//     LDS: xs [64][68 dw] (x bf16 / later h1 f32), w1t [64][68 dw] (K=128!),
//     w2t [32][36 dw]. Total 39424 B -> 4 blocks/CU. Strides bank-rotating. ---
#define NPB 64
#define XDW 68    // x / h1 / w1t row stride in dwords
#define WDW 36    // w2t / h2 row stride in dwords

__global__ __launch_bounds__(256) void mlp_kernel(
    const float* __restrict__ feat, const unsigned short* __restrict__ X3,
    const int* __restrict__ invidx,
    const unsigned* __restrict__ W1b, const float* __restrict__ b1,
    const unsigned* __restrict__ W2b, const float* __restrict__ b2,
    const float* __restrict__ W3, const float* __restrict__ b3,
    const float* __restrict__ W4, float* __restrict__ out) {
    __shared__ unsigned smem[4352 + 4352 + 1152];   // 39424 B
    unsigned* xs  = smem;                   // [64][68] x as bf16 pairs (64 used/row)
    float*    h1f = (float*)smem;           // overlay after L1: [64][68] f32 (64 used)
    unsigned* w1t = smem + 4352;            // [64][68] bf16 pairs (64 used/row)
    float*    h2f = (float*)(smem + 4352);  // overlay after L2: [64][36] f32 (32 used)
    unsigned* w2t = smem + 4352 + 4352;     // [32][36] (32 used/row)

    int tid = threadIdx.x;
    int nb = blockIdx.x * NPB;

    // stage x: 64 rows x 64 uints (bf16 pairs); node wave-uniform per iter
    #pragma unroll 4
    for (int it = 0; it < 16; ++it) {
        int i = it * 256 + tid;
        int node = i >> 6, u = i & 63;
        int n = nb + node;
        unsigned p = 0;
        if (n < NN) {
            int q = invidx[n];
            if (q >= 0) p = ((const unsigned*)X3)[(size_t)q * 64 + u];
            else { float2 f = ((const float2*)feat)[(size_t)n * 64 + u]; p = pk2(f.x, f.y); }
        }
        xs[node * XDW + u] = p;
    }
    // stage W1^T: 4096 uints as 1024 uint4 (coalesced global, 2-way LDS)
    #pragma unroll
    for (int it = 0; it < 4; ++it) {
        int i = it * 256 + tid;            // uint4 index [0,1024)
        int j = i >> 4, s4 = i & 15;       // row j, 4-dword chunk s4
        uint4 wv = ((const uint4*)W1b)[i];
        *(uint4*)(w1t + j * XDW + s4 * 4) = wv;
    }
    // stage W2^T: 1024 uints = 256 uint4
    {
        int j = tid >> 3, s4 = tid & 7;
        uint4 wv = ((const uint4*)W2b)[tid];
        *(uint4*)(w2t + j * WDW + s4 * 4) = wv;
    }
    __syncthreads();

    int lane = tid & 63, w = tid >> 6;
    int p = lane & 15, q = lane >> 4;

    // ---- L1: nodes w*16..w*16+15 (A m=p), 64 outputs ----
    bf16x8 af[4];
    #pragma unroll
    for (int kc = 0; kc < 4; ++kc)
        af[kc] = *(const bf16x8*)((const short*)(xs + (w * 16 + p) * XDW + kc * 16 + q * 4));

    f32x4 acc[4];
    #pragma unroll
    for (int jt = 0; jt < 4; ++jt) {
        float bv = b1[jt * 16 + p];
        acc[jt][0] = bv; acc[jt][1] = bv; acc[jt][2] = bv; acc[jt][3] = bv;
    }
    #pragma unroll
    for (int jt = 0; jt < 4; ++jt) {
        #pragma unroll
        for (int kc = 0; kc < 4; ++kc) {
            bf16x8 bf = *(const bf16x8*)((const short*)(w1t + (jt * 16 + p) * XDW + kc * 16 + q * 4));
            acc[jt] = __builtin_amdgcn_mfma_f32_16x16x32_bf16(af[kc], bf, acc[jt], 0, 0, 0);
        }
    }
    __syncthreads();   // xs dead; overlay h1 (f32)
    #pragma unroll
    for (int jt = 0; jt < 4; ++jt) {
        #pragma unroll
        for (int r = 0; r < 4; ++r) {
            float v = acc[jt][r];
            v = v > 0.f ? v : 0.01f * v;
            h1f[(w * 16 + q * 4 + r) * XDW + jt * 16 + p] = v;
        }
    }
    __syncthreads();

    // ---- L2: A-frag from f32 h1 (pack to bf16), B from w2t ----
    bf16x8 a2f[2];
    #pragma unroll
    for (int kc = 0; kc < 2; ++kc) {
        const float* hp = h1f + (w * 16 + p) * XDW + kc * 32 + q * 8;
        f32x4 v0 = *(const f32x4*)hp;
        f32x4 v1 = *(const f32x4*)(hp + 4);
        unsigned u0 = pk2(v0[0], v0[1]), u1 = pk2(v0[2], v0[3]);
        unsigned u2 = pk2(v1[0], v1[1]), u3 = pk2(v1[2], v1[3]);
        uint4 uu = make_uint4(u0, u1, u2, u3);
        a2f[kc] = *(const bf16x8*)&uu;
    }
    f32x4 acc2[2];
    #pragma unroll
    for (int jt = 0; jt < 2; ++jt) {
        float bv = b2[jt * 16 + p];
        acc2[jt][0] = bv; acc2[jt][1] = bv; acc2[jt][2] = bv; acc2[jt][3] = bv;
        #pragma unroll
        for (int kc = 0; kc < 2; ++kc) {
            bf16x8 bf = *(const bf16x8*)((const short*)(w2t + (jt * 16 + p) * WDW + kc * 16 + q * 4));
            acc2[jt] = __builtin_amdgcn_mfma_f32_16x16x32_bf16(a2f[kc], bf, acc2[jt], 0, 0, 0);
        }
    }
    __syncthreads();   // w1t region dead; overlay h2f
    #pragma unroll
    for (int jt = 0; jt < 2; ++jt) {
        #pragma unroll
        for (int r = 0; r < 4; ++r) {
            float v = acc2[jt][r];
            v = v > 0.f ? v : 0.01f * v;
            h2f[(w * 16 + q * 4 + r) * WDW + jt * 16 + p] = v;
        }
    }
    __syncthreads();

    // ---- L3+L4 scalar tail: each wave its 16 nodes; q-groups redundant ----
    int node = w * 16 + p;
    float a3[21];
    #pragma unroll
    for (int j = 0; j < 21; ++j) a3[j] = b3[j];
    #pragma unroll 4
    for (int k = 0; k < 32; ++k) {
        float hk = h2f[node * WDW + k];
        fma21(hk, W3 + k * 21, a3);
    }
    float s = 0.f;
    #pragma unroll
    for (int j = 0; j < 21; ++j) {
        float vj = a3[j] > 0.f ? a3[j] : 0.01f * a3[j];
        s = fmaf(vj, W4[j], s);
    }
    if (q == 0) {
        int n = nb + node;
        if (n < NN) out[n] = 1.f / (1.f + expf(-s));
    }
}

extern "C" void kernel_launch(void* const* d_in, const int* in_sizes, int n_in,
                              void* d_out, int out_size, void* d_ws, size_t ws_size,
                              hipStream_t stream) {
    const float* feat = (const float*)d_in[0];
    const int*   index = (const int*)d_in[1];
    const int*   erow = (const int*)d_in[2];
    const int*   ecol = (const int*)d_in[3];
    const float* evalp = (const float*)d_in[4];
    const float* W1 = (const float*)d_in[5];
    const float* b1 = (const float*)d_in[6];
    const float* W2 = (const float*)d_in[7];
    const float* b2 = (const float*)d_in[8];
    const float* W3 = (const float*)d_in[9];
    const float* b3 = (const float*)d_in[10];
    const float* W4 = (const float*)d_in[11];
    float* out = (float*)d_out;

    char* ws = (char*)d_ws;
    size_t off = 0;
    auto alloc = [&](size_t bytes) -> void* {
        void* p = ws + off;
        off += (bytes + 255) & ~(size_t)255;
        return p;
    };
    unsigned long long* dcpack = (unsigned long long*)alloc((size_t)MM * 8);
    float* dis     = (float*)alloc((size_t)MM * 4);
    int*   cnt     = (int*)  alloc((size_t)MM * 4);
    int*   rowptr  = (int*)  alloc((size_t)(MM + 1) * 4);
    int*   partial = (int*)  alloc((size_t)MM * 4);
    int*   bsum    = (int*)  alloc((size_t)NB * 4);
    int*   boff    = (int*)  alloc((size_t)NB * 4);
    int*   slot    = (int*)  alloc((size_t)EE * 4);
    int*   col_s   = (int*)  alloc((size_t)EE * 4);
    float* val_s   = (float*)alloc((size_t)EE * 4);
    int*   invidx  = (int*)  alloc((size_t)NN * 4);
    unsigned* W1b  = (unsigned*)alloc(4096 * 4);
    unsigned* W2b  = (unsigned*)alloc(1024 * 4);
    unsigned*       X0b = (unsigned*)      alloc((size_t)MM * DD * 2);
    unsigned short* Xa  = (unsigned short*)alloc((size_t)MM * DD * 2);
    unsigned short* Xb  = (unsigned short*)alloc((size_t)MM * DD * 2);

    hipMemsetAsync(dcpack, 0, (size_t)MM * 8, stream);

    deg_count_kernel<<<(EE + 255) / 256, 256, 0, stream>>>(erow, evalp, dcpack, slot, invidx);
    fused_setup_kernel<<<NB, 256, 0, stream>>>(dcpack, dis, index, invidx, cnt, partial, bsum);
    scanB_kernel<<<1, 64, 0, stream>>>(bsum, boff);
    scanC_kernel<<<(MM + 255) / 256, 256, 0, stream>>>(partial, cnt, boff, rowptr);
    scatter_kernel<<<(EE + 255) / 256, 256, 0, stream>>>(erow, ecol, evalp, dis,
                                                         rowptr, slot, col_s, val_s);
    cvt_kernel<<<(MM * 64 + 255) / 256, 256, 0, stream>>>(feat, index, X0b, W1, W2, W1b, W2b);

    spmm_kernel<<<(MM + 15) / 16, 256, 0, stream>>>(rowptr, col_s, val_s,
                                                    (const unsigned short*)X0b, Xa);
    spmm_kernel<<<(MM + 15) / 16, 256, 0, stream>>>(rowptr, col_s, val_s, Xa, Xb);
    spmm_kernel<<<(MM + 15) / 16, 256, 0, stream>>>(rowptr, col_s, val_s, Xb, Xa);

    mlp_kernel<<<(NN + NPB - 1) / NPB, 256, 0, stream>>>(feat, Xa, invidx,
                                                         W1b, b1, W2b, b2, W3, b3, W4, out);
}

// Round 11
// 265.536 us; speedup vs baseline: 1.0164x; 1.0164x over previous
//
#include <hip/hip_runtime.h>
#include <math.h>

#define NN 100000
#define MM 50000
#define EE 600000
#define DD 128
#define NB 196     // ceil(MM/256)
#define NNP 100096 // NN padded to block multiple

typedef short bf16x8 __attribute__((ext_vector_type(8)));
typedef float f32x4 __attribute__((ext_vector_type(4)));

// ---- bf16 helpers (upper 16 bits of f32; RNE rounding) ----
__device__ __forceinline__ float bl(unsigned u) { return __uint_as_float(u << 16); }
__device__ __forceinline__ float bh(unsigned u) { return __uint_as_float(u & 0xFFFF0000u); }
__device__ __forceinline__ unsigned rne(float f) {
    unsigned u = __float_as_uint(f);
    return (u + 0x7FFFu + ((u >> 16) & 1u)) >> 16;
}
__device__ __forceinline__ unsigned pk2(float a, float b) { return rne(a) | (rne(b) << 16); }

// a[0..7] += v * bf16x8(u)   (spmm inner op)
__device__ __forceinline__ void fmab8(float v, uint4 u, float* a) {
    a[0] = fmaf(v, bl(u.x), a[0]); a[1] = fmaf(v, bh(u.x), a[1]);
    a[2] = fmaf(v, bl(u.y), a[2]); a[3] = fmaf(v, bh(u.y), a[3]);
    a[4] = fmaf(v, bl(u.z), a[4]); a[5] = fmaf(v, bh(u.z), a[5]);
    a[6] = fmaf(v, bl(u.w), a[6]); a[7] = fmaf(v, bh(u.w), a[7]);
}

__device__ __forceinline__ void fma21(float h, const float* wrow, float* a) {
    #pragma unroll
    for (int j = 0; j < 21; ++j) a[j] = fmaf(h, wrow[j], a[j]);
}

// --- degree+count via ONE packed 64-bit atomic per edge ---
__global__ void deg_count_kernel(const int* __restrict__ row, const float* __restrict__ val,
                                 unsigned long long* __restrict__ dcpack,
                                 int* __restrict__ slot, int* __restrict__ invidx) {
    int e = blockIdx.x * 256 + threadIdx.x;
    if (e < NN) invidx[e] = -1;
    if (e < EE) {
        int r = row[e];
        unsigned long long add = (1ULL << 44) | (unsigned long long)(val[e] * 4294967296.0f);
        unsigned long long old = atomicAdd(&dcpack[r], add);
        slot[e] = (int)(old >> 44);
    }
}

// --- fused: unpack deg/cnt; dis; invidx; scanA ---
__global__ void fused_setup_kernel(const unsigned long long* __restrict__ dcpack,
                                   float* __restrict__ dis,
                                   const int* __restrict__ index, int* __restrict__ invidx,
                                   int* __restrict__ cnt, int* __restrict__ partial,
                                   int* __restrict__ bsum) {
    __shared__ int ws[4];
    int tid = threadIdx.x, lane = tid & 63, w = tid >> 6;
    int i = blockIdx.x * 256 + tid;
    int v = 0;
    if (i < MM) {
        unsigned long long pkv = dcpack[i];
        v = (int)(pkv >> 44);
        float dsum = (float)(pkv & ((1ULL << 44) - 1)) * (1.0f / 4294967296.0f);
        dis[i] = rsqrtf(dsum + 1e-8f);
        invidx[index[i]] = i;
        cnt[i] = v;
    }
    int x = v;
    #pragma unroll
    for (int off = 1; off < 64; off <<= 1) {
        int t = __shfl_up(x, off, 64);
        if (lane >= off) x += t;
    }
    if (lane == 63) ws[w] = x;
    __syncthreads();
    int add = 0;
    for (int q = 0; q < w; ++q) add += ws[q];
    x += add;
    if (i < MM) partial[i] = x;
    if (tid == 255) bsum[blockIdx.x] = x;
}

__global__ void scanB_kernel(const int* __restrict__ bsum, int* __restrict__ boff) {
    int lane = threadIdx.x;  // 64 threads
    int carry = 0;
    for (int base = 0; base < NB; base += 64) {
        int v = (base + lane < NB) ? bsum[base + lane] : 0;
        int x = v;
        #pragma unroll
        for (int off = 1; off < 64; off <<= 1) {
            int t = __shfl_up(x, off, 64);
            if (lane >= off) x += t;
        }
        if (base + lane < NB) boff[base + lane] = carry + x - v;
        carry += __shfl(x, 63);
    }
}

__global__ void scanC_kernel(const int* __restrict__ partial, const int* __restrict__ cnt,
                             const int* __restrict__ boff, int* __restrict__ rowptr) {
    int i = blockIdx.x * 256 + threadIdx.x;
    if (i < MM) rowptr[i] = partial[i] - cnt[i] + boff[i >> 8];
    if (i == 0) rowptr[MM] = EE;
}

// --- bucket edges by row (atomic-free) ---
__global__ void scatter_kernel(const int* __restrict__ row, const int* __restrict__ col,
                               const float* __restrict__ val, const float* __restrict__ dis,
                               const int* __restrict__ rowptr, const int* __restrict__ slot,
                               int* __restrict__ col_s, float* __restrict__ val_s) {
    int e = blockIdx.x * 256 + threadIdx.x;
    if (e < EE) {
        int r = row[e], c = col[e];
        int pos = rowptr[r] + slot[e];
        col_s[pos] = c;
        val_s[pos] = val[e] * dis[r] * dis[c];
    }
}

// --- X0b = bf16(features[index]); Xfull backfill for non-propagated nodes;
//     W1b/W2b = transposed packed bf16 weights ---
__global__ void cvt_kernel(const float* __restrict__ feat, const int* __restrict__ index,
                           const int* __restrict__ invidx,
                           unsigned* __restrict__ X0b, unsigned* __restrict__ Xfull,
                           const float* __restrict__ W1, const float* __restrict__ W2,
                           unsigned* __restrict__ W1b, unsigned* __restrict__ W2b) {
    int i = blockIdx.x * 256 + threadIdx.x;   // grid covers NN*64
    int n = i >> 6, u = i & 63;
    if (n < NN && invidx[n] < 0) {            // backfill: bf16(feat) row
        float2 f = ((const float2*)feat)[(size_t)n * 64 + u];
        Xfull[(size_t)n * 64 + u] = pk2(f.x, f.y);
    }
    if (i < MM * 64) {                        // X0b = bf16(feat[index])
        int idx = index[n];
        float2 f = ((const float2*)feat)[(size_t)idx * 64 + u];
        X0b[i] = pk2(f.x, f.y);
    }
    if (i < 4096) {          // W1^T: [j=0..63][kp=0..63]  (K=128)
        int j = i >> 6, kp = i & 63;
        W1b[i] = pk2(W1[(2 * kp) * 64 + j], W1[(2 * kp + 1) * 64 + j]);
    } else if (i < 5120) {   // W2^T: [j=0..31][kp=0..31]
        int t = i - 4096;
        int j = t >> 5, kp = t & 31;
        W2b[t] = pk2(W2[(2 * kp) * 32 + j], W2[(2 * kp + 1) * 32 + j]);
    }
}

// --- SpMM on bf16 tables: 16-lane group per row, 4 groups/wave; 1 uint4 gather/edge.
//     If remap != null, row r writes to Y[remap[r]] (layer 3 -> Xfull). ---
__global__ __launch_bounds__(256) void spmm_kernel(
    const int* __restrict__ rowptr, const int* __restrict__ cols,
    const float* __restrict__ vals, const unsigned short* __restrict__ X,
    unsigned short* __restrict__ Y, const int* __restrict__ remap) {
    int lane = threadIdx.x & 63;
    int wid = threadIdx.x >> 6;
    int g = lane >> 4, sub = lane & 15;
    int r = blockIdx.x * 16 + wid * 4 + g;
    bool valid = (r < MM);
    int rc = valid ? r : (MM - 1);
    int s = rowptr[rc], e = rowptr[rc + 1];
    const uint4* __restrict__ X4 = (const uint4*)X;
    float a[8] = {0.f, 0.f, 0.f, 0.f, 0.f, 0.f, 0.f, 0.f};
    for (int base = s; base < e; base += 16) {
        int cnt = min(16, e - base);
        int c = 0; float v = 0.f;
        if (sub < cnt) { c = cols[base + sub]; v = vals[base + sub]; }
        int j = 0;
        for (; j + 4 <= cnt; j += 4) {
            int c0 = __shfl(c, g * 16 + j);     float v0 = __shfl(v, g * 16 + j);
            int c1 = __shfl(c, g * 16 + j + 1); float v1 = __shfl(v, g * 16 + j + 1);
            int c2 = __shfl(c, g * 16 + j + 2); float v2 = __shfl(v, g * 16 + j + 2);
            int c3 = __shfl(c, g * 16 + j + 3); float v3 = __shfl(v, g * 16 + j + 3);
            uint4 u0 = X4[(size_t)c0 * 16 + sub];
            uint4 u1 = X4[(size_t)c1 * 16 + sub];
            uint4 u2 = X4[(size_t)c2 * 16 + sub];
            uint4 u3 = X4[(size_t)c3 * 16 + sub];
            fmab8(v0, u0, a);
            fmab8(v1, u1, a);
            fmab8(v2, u2, a);
            fmab8(v3, u3, a);
        }
        for (; j < cnt; ++j) {
            int cc = __shfl(c, g * 16 + j); float vv = __shfl(v, g * 16 + j);
            uint4 u0 = X4[(size_t)cc * 16 + sub];
            fmab8(vv, u0, a);
        }
    }
    if (valid) {
        int dst = remap ? remap[rc] : rc;
        uint4 o;
        o.x = pk2(a[0], a[1]); o.y = pk2(a[2], a[3]);
        o.z = pk2(a[4], a[5]); o.w = pk2(a[6], a[7]);
        ((uint4*)Y)[(size_t)dst * 16 + sub] = o;
    }
}

// --- MFMA MLP v3: 64 nodes/block (4 waves x 16 nodes), BARRIER-FREE.
//     A-frags: direct global loads from Xfull (consecutive 256B rows).
//     B-frags: direct global loads from pre-packed W1b/W2b (L2-hot).
//     LDS: per-wave private h1/h2 transpose buffer only (17408 B). ---
__global__ __launch_bounds__(256) void mlp_kernel(
    const unsigned* __restrict__ Xfull,
    const unsigned* __restrict__ W1b, const float* __restrict__ b1,
    const unsigned* __restrict__ W2b, const float* __restrict__ b2,
    const float* __restrict__ W3, const float* __restrict__ b3,
    const float* __restrict__ W4, float* __restrict__ out) {
    __shared__ float hls[4 * 1088];   // per-wave 16x68-f32 region
    int tid = threadIdx.x;
    int lane = tid & 63, w = tid >> 6;
    int p = lane & 15, q = lane >> 4;
    float* hw = hls + w * 1088;
    int nb = blockIdx.x * 64;
    int node = nb + w * 16 + p;       // guaranteed < NNP (padded table)

    // ---- L1: A direct from Xfull, B direct from W1b ----
    bf16x8 af[4];
    #pragma unroll
    for (int kc = 0; kc < 4; ++kc) {
        uint4 u = *(const uint4*)(Xfull + (size_t)node * 64 + kc * 16 + q * 4);
        af[kc] = *(const bf16x8*)&u;
    }
    f32x4 acc[4];
    #pragma unroll
    for (int jt = 0; jt < 4; ++jt) {
        float bv = b1[jt * 16 + p];
        acc[jt][0] = bv; acc[jt][1] = bv; acc[jt][2] = bv; acc[jt][3] = bv;
    }
    #pragma unroll
    for (int jt = 0; jt < 4; ++jt) {
        #pragma unroll
        for (int kc = 0; kc < 4; ++kc) {
            uint4 u = *(const uint4*)(W1b + (jt * 16 + p) * 64 + kc * 16 + q * 4);
            bf16x8 bf = *(const bf16x8*)&u;
            acc[jt] = __builtin_amdgcn_mfma_f32_16x16x32_bf16(af[kc], bf, acc[jt], 0, 0, 0);
        }
    }
    // h1 -> wave-private LDS (C layout: node=q*4+r, col=jt*16+p); leaky ReLU
    #pragma unroll
    for (int jt = 0; jt < 4; ++jt) {
        #pragma unroll
        for (int r = 0; r < 4; ++r) {
            float v = acc[jt][r];
            v = v > 0.f ? v : 0.01f * v;
            hw[(q * 4 + r) * 68 + jt * 16 + p] = v;
        }
    }
    // ---- L2: A from hw (pack f32->bf16), B direct from W2b ----
    bf16x8 a2f[2];
    #pragma unroll
    for (int kc = 0; kc < 2; ++kc) {
        const float* hp = hw + p * 68 + kc * 32 + q * 8;
        f32x4 v0 = *(const f32x4*)hp;
        f32x4 v1 = *(const f32x4*)(hp + 4);
        uint4 uu = make_uint4(pk2(v0[0], v0[1]), pk2(v0[2], v0[3]),
                              pk2(v1[0], v1[1]), pk2(v1[2], v1[3]));
        a2f[kc] = *(const bf16x8*)&uu;
    }
    f32x4 acc2[2];
    #pragma unroll
    for (int jt = 0; jt < 2; ++jt) {
        float bv = b2[jt * 16 + p];
        acc2[jt][0] = bv; acc2[jt][1] = bv; acc2[jt][2] = bv; acc2[jt][3] = bv;
        #pragma unroll
        for (int kc = 0; kc < 2; ++kc) {
            uint4 u = *(const uint4*)(W2b + (jt * 16 + p) * 32 + kc * 16 + q * 4);
            bf16x8 bf = *(const bf16x8*)&u;
            acc2[jt] = __builtin_amdgcn_mfma_f32_16x16x32_bf16(a2f[kc], bf, acc2[jt], 0, 0, 0);
        }
    }
    // h2 -> same wave-private LDS (all h1 reads by this wave precede, in-order LDS)
    #pragma unroll
    for (int jt = 0; jt < 2; ++jt) {
        #pragma unroll
        for (int r = 0; r < 4; ++r) {
            float v = acc2[jt][r];
            v = v > 0.f ? v : 0.01f * v;
            hw[(q * 4 + r) * 36 + jt * 16 + p] = v;
        }
    }
    // ---- L3+L4 scalar tail (q-groups redundant; W3/W4 via s_load) ----
    float a3[21];
    #pragma unroll
    for (int j = 0; j < 21; ++j) a3[j] = b3[j];
    #pragma unroll 4
    for (int k = 0; k < 32; ++k) {
        float hk = hw[p * 36 + k];
        fma21(hk, W3 + k * 21, a3);
    }
    float s = 0.f;
    #pragma unroll
    for (int j = 0; j < 21; ++j) {
        float vj = a3[j] > 0.f ? a3[j] : 0.01f * a3[j];
        s = fmaf(vj, W4[j], s);
    }
    if (q == 0) {
        int n = nb + w * 16 + p;
        if (n < NN) out[n] = 1.f / (1.f + expf(-s));
    }
}

extern "C" void kernel_launch(void* const* d_in, const int* in_sizes, int n_in,
                              void* d_out, int out_size, void* d_ws, size_t ws_size,
                              hipStream_t stream) {
    const float* feat = (const float*)d_in[0];
    const int*   index = (const int*)d_in[1];
    const int*   erow = (const int*)d_in[2];
    const int*   ecol = (const int*)d_in[3];
    const float* evalp = (const float*)d_in[4];
    const float* W1 = (const float*)d_in[5];
    const float* b1 = (const float*)d_in[6];
    const float* W2 = (const float*)d_in[7];
    const float* b2 = (const float*)d_in[8];
    const float* W3 = (const float*)d_in[9];
    const float* b3 = (const float*)d_in[10];
    const float* W4 = (const float*)d_in[11];
    float* out = (float*)d_out;

    char* ws = (char*)d_ws;
    size_t off = 0;
    auto alloc = [&](size_t bytes) -> void* {
        void* p = ws + off;
        off += (bytes + 255) & ~(size_t)255;
        return p;
    };
    unsigned long long* dcpack = (unsigned long long*)alloc((size_t)MM * 8);
    float* dis     = (float*)alloc((size_t)MM * 4);
    int*   cnt     = (int*)  alloc((size_t)MM * 4);
    int*   rowptr  = (int*)  alloc((size_t)(MM + 1) * 4);
    int*   partial = (int*)  alloc((size_t)MM * 4);
    int*   bsum    = (int*)  alloc((size_t)NB * 4);
    int*   boff    = (int*)  alloc((size_t)NB * 4);
    int*   slot    = (int*)  alloc((size_t)EE * 4);
    int*   col_s   = (int*)  alloc((size_t)EE * 4);
    float* val_s   = (float*)alloc((size_t)EE * 4);
    int*   invidx  = (int*)  alloc((size_t)NN * 4);
    unsigned* W1b  = (unsigned*)alloc(4096 * 4);
    unsigned* W2b  = (unsigned*)alloc(1024 * 4);
    unsigned*       X0b   = (unsigned*)      alloc((size_t)MM * DD * 2);
    unsigned short* Xa    = (unsigned short*)alloc((size_t)MM * DD * 2);
    unsigned short* Xb    = (unsigned short*)alloc((size_t)MM * DD * 2);
    unsigned*       Xfull = (unsigned*)      alloc((size_t)NNP * DD * 2);

    hipMemsetAsync(dcpack, 0, (size_t)MM * 8, stream);

    deg_count_kernel<<<(EE + 255) / 256, 256, 0, stream>>>(erow, evalp, dcpack, slot, invidx);
    fused_setup_kernel<<<NB, 256, 0, stream>>>(dcpack, dis, index, invidx, cnt, partial, bsum);
    scanB_kernel<<<1, 64, 0, stream>>>(bsum, boff);
    scanC_kernel<<<(MM + 255) / 256, 256, 0, stream>>>(partial, cnt, boff, rowptr);
    scatter_kernel<<<(EE + 255) / 256, 256, 0, stream>>>(erow, ecol, evalp, dis,
                                                         rowptr, slot, col_s, val_s);
    cvt_kernel<<<(NN * 64 + 255) / 256, 256, 0, stream>>>(feat, index, invidx, X0b, Xfull,
                                                          W1, W2, W1b, W2b);

    spmm_kernel<<<(MM + 15) / 16, 256, 0, stream>>>(rowptr, col_s, val_s,
                                                    (const unsigned short*)X0b, Xa, nullptr);
    spmm_kernel<<<(MM + 15) / 16, 256, 0, stream>>>(rowptr, col_s, val_s, Xa, Xb, nullptr);
    spmm_kernel<<<(MM + 15) / 16, 256, 0, stream>>>(rowptr, col_s, val_s, Xb,
                                                    (unsigned short*)Xfull, index);

    mlp_kernel<<<(NNP + 63) / 64, 256, 0, stream>>>(Xfull, W1b, b1, W2b, b2,
                                                    W3, b3, W4, out);
}